// Round 1
// 225.743 us; speedup vs baseline: 1.0129x; 1.0129x over previous
//
#include <hip/hip_runtime.h>

typedef unsigned short u16;
typedef unsigned int   u32;
typedef short s16x8 __attribute__((ext_vector_type(8)));   // 8 x bf16 (4 VGPRs)
typedef float f32x4 __attribute__((ext_vector_type(4)));

// ---- workspace layout (bytes); total footprint 34,340,864 (proven safe) ----
#define WS_STATSV 0          // 8192 * float2
#define WS_STATSC 65536      // 8192 * float2
#define WS_WT_VQK 131072     // [512][256] bf16
#define WS_WT_CQK 393216     // [512][64]
#define WS_WT_VV  458752     // [256][256]
#define WS_WT_CV  589824     // [256][64]
#define WS_WT_OV  622592     // [256][256]
#define WS_WT_OC  753664     // [64][256]
#define WS_Q      786432     // [16][2048][128] bf16  (qv|qc per head; Q pre-scaled by log2e/8)
#define WS_K      9175040    // [16][2048][128] bf16
#define WS_VT     17563648   // [16][128][2048] bf16 (V^T per bh; d: vv 0..63, vc 64..127)
#define WS_OV     25952256   // [8192][256] bf16
#define WS_OC     30146560   // [8192][256] bf16  (ends 34,340,864)

__device__ __forceinline__ float bf2f(u16 h){
  union { u32 u; float f; } x; x.u = ((u32)h) << 16; return x.f;
}
__device__ __forceinline__ u16 f2bf(float f){
  union { float f; u32 u; } x; x.f = f;
  u32 u = x.u; u += 0x7fffu + ((u >> 16) & 1u);
  return (u16)(u >> 16);
}
__device__ __forceinline__ f32x4 mfma16(s16x8 a, s16x8 b, f32x4 c){
  return __builtin_amdgcn_mfma_f32_16x16x32_bf16(a, b, c, 0, 0, 0);
}
// async global->LDS DMA, 16B per lane; LDS dest must be uniform-base + lane*16 (it is).
__device__ __forceinline__ void async16(const u16* g, u16* l){
  __builtin_amdgcn_global_load_lds(
      (const __attribute__((address_space(1))) u32*)(const void*)g,
      (__attribute__((address_space(3))) u32*)(void*)l, 16, 0, 0);
}

// ---------------- fused: LN row stats (bids 0..4095) + weight transpose (4096..4255) ----------------
__global__ __launch_bounds__(256) void k_prep(const float* V, const float* C,
    const float* Wvqk, const float* Wcqk, const float* Wvv, const float* Wcv,
    const float* Wov, const float* Woc, char* ws){
  int bid = blockIdx.x;
  if (bid < 4096){
    int wid = threadIdx.x >> 6, lane = threadIdx.x & 63;
    float2* sV = (float2*)(ws + WS_STATSV);
    float2* sC = (float2*)(ws + WS_STATSC);
    float s = 0.f, s2 = 0.f; int row; float2* dst; float invn;
    if (bid < 2048){
      row = bid*4 + wid;
      const float4* p = (const float4*)(V + row*256);
      float4 v = p[lane];
      s = v.x+v.y+v.z+v.w; s2 = v.x*v.x+v.y*v.y+v.z*v.z+v.w*v.w;
      dst = sV; invn = 1.0f/256.0f;
    } else {
      row = (bid-2048)*4 + wid;
      float x = C[row*64 + lane];
      s = x; s2 = x*x;
      dst = sC; invn = 1.0f/64.0f;
    }
    for (int d=1; d<64; d<<=1){ s += __shfl_xor(s,d); s2 += __shfl_xor(s2,d); }
    if (lane == 0){
      float m = s*invn; float var = s2*invn - m*m; if (var < 0.f) var = 0.f;
      float rstd = rsqrtf(var + 1e-5f);
      float2 o; o.x = rstd; o.y = -m*rstd;
      dst[row] = o;
    }
  } else {
    int tb = bid - 4096;
    const float* src; u16* dst; int K, N, rel;
    if      (tb <  64){ src=Wvqk; dst=(u16*)(ws+WS_WT_VQK); K=256; N=512; rel=tb;     }
    else if (tb <  80){ src=Wcqk; dst=(u16*)(ws+WS_WT_CQK); K=64;  N=512; rel=tb-64;  }
    else if (tb < 112){ src=Wvv;  dst=(u16*)(ws+WS_WT_VV);  K=256; N=256; rel=tb-80;  }
    else if (tb < 120){ src=Wcv;  dst=(u16*)(ws+WS_WT_CV);  K=64;  N=256; rel=tb-112; }
    else if (tb < 152){ src=Wov;  dst=(u16*)(ws+WS_WT_OV);  K=256; N=256; rel=tb-120; }
    else              { src=Woc;  dst=(u16*)(ws+WS_WT_OC);  K=256; N=64;  rel=tb-152; }
    int e = rel*2048 + threadIdx.x*8;
    int k = e / N, n0 = e % N;
    float4 t0 = *(const float4*)(src + e);
    float4 t1 = *(const float4*)(src + e + 4);
    dst[(n0+0)*K + k] = f2bf(t0.x);
    dst[(n0+1)*K + k] = f2bf(t0.y);
    dst[(n0+2)*K + k] = f2bf(t0.z);
    dst[(n0+3)*K + k] = f2bf(t0.w);
    dst[(n0+4)*K + k] = f2bf(t1.x);
    dst[(n0+5)*K + k] = f2bf(t1.y);
    dst[(n0+6)*K + k] = f2bf(t1.z);
    dst[(n0+7)*K + k] = f2bf(t1.w);
  }
}

__device__ __forceinline__ s16x8 ln_frag(const float* A, const float* g, const float* bb,
                                         int base, int k0, float2 stt){
  float4 x0 = *(const float4*)(A + base + k0);
  float4 x1 = *(const float4*)(A + base + k0 + 4);
  float4 g0 = *(const float4*)(g + k0);
  float4 g1 = *(const float4*)(g + k0 + 4);
  float4 b0 = *(const float4*)(bb + k0);
  float4 b1 = *(const float4*)(bb + k0 + 4);
  s16x8 af;
  af[0] = (short)f2bf(fmaf(fmaf(x0.x, stt.x, stt.y), g0.x, b0.x));
  af[1] = (short)f2bf(fmaf(fmaf(x0.y, stt.x, stt.y), g0.y, b0.y));
  af[2] = (short)f2bf(fmaf(fmaf(x0.z, stt.x, stt.y), g0.z, b0.z));
  af[3] = (short)f2bf(fmaf(fmaf(x0.w, stt.x, stt.y), g0.w, b0.w));
  af[4] = (short)f2bf(fmaf(fmaf(x1.x, stt.x, stt.y), g1.x, b1.x));
  af[5] = (short)f2bf(fmaf(fmaf(x1.y, stt.x, stt.y), g1.y, b1.y));
  af[6] = (short)f2bf(fmaf(fmaf(x1.z, stt.x, stt.y), g1.z, b1.z));
  af[7] = (short)f2bf(fmaf(fmaf(x1.w, stt.x, stt.y), g1.w, b1.w));
  return af;
}

// ---------------- fused projections v2 (more waves):
// bids [0,512) V-qk 16-row, [512,1024) C-qk 16-row, [1024,1280) V-v 32-row, [1280,1536) C-v 32-row
__global__ __launch_bounds__(256) void k_proj(const float* V, const float* C,
    const float* vg, const float* vb, const float* cgam, const float* cbet,
    const float* bvqk, const float* bcqk, const float* rmsv, const float* rmsc,
    const float* bvv, const float* bcv, char* ws){
  __shared__ float ssl[4][16];
  int bid = blockIdx.x;
  int tid = threadIdx.x, lane = tid & 63, w = tid >> 6;
  int c = lane & 15, q = lane >> 4;

  if (bid < 1024){
    bool csd = bid >= 512;
    int rb = (bid & 511) * 16;
    const float* A   = csd ? C : V;
    int K            = csd ? 64 : 256;
    const float2* st = (const float2*)(ws + (csd ? WS_STATSC : WS_STATSV));
    const float* g   = csd ? cgam : vg;
    const float* bb  = csd ? cbet : vb;
    const u16* Wt    = (const u16*)(ws + (csd ? WS_WT_CQK : WS_WT_VQK));
    const float* bias= csd ? bcqk : bvqk;
    const float* rms = csd ? rmsc : rmsv;
    int dOff         = csd ? 64 : 0;

    int row = rb + c;
    float2 stt = st[row];
    int j0 = w * 128;                 // wave = 128-col group of the 512

    f32x4 acc[8];
    #pragma unroll
    for (int f=0; f<8; f++){ f32x4 z = {0.f,0.f,0.f,0.f}; acc[f] = z; }

    int nkc = K >> 5;
    for (int kc=0; kc<nkc; kc++){
      int k0 = kc*32 + q*8;
      s16x8 af = ln_frag(A, g, bb, row*K, k0, stt);
      #pragma unroll
      for (int f=0; f<8; f++){
        s16x8 bfr = *(const s16x8*)(Wt + (j0 + f*16 + c)*K + k0);
        acc[f] = mfma16(af, bfr, acc[f]);
      }
    }

    float ss[4] = {0.f,0.f,0.f,0.f};
    float rsv[8];
    #pragma unroll
    for (int f=0; f<8; f++){
      int j = j0 + f*16 + c;
      float bsv = bias[j]; rsv[f] = rms[j];
      #pragma unroll
      for (int i=0;i<4;i++){ acc[f][i] += bsv; ss[i] += acc[f][i]*acc[f][i]; }
    }
    #pragma unroll
    for (int d=1; d<16; d<<=1){
      #pragma unroll
      for (int i=0;i<4;i++) ss[i] += __shfl_xor(ss[i], d);
    }
    if (c == 0){
      #pragma unroll
      for (int i=0;i<4;i++) ssl[w][q*4 + i] = ss[i];
    }
    __syncthreads();
    float rmsr[4];
    #pragma unroll
    for (int i=0;i<4;i++){
      int rl = q*4 + i;
      float tot = ssl[0][rl] + ssl[1][rl] + ssl[2][rl] + ssl[3][rl];
      rmsr[i] = rsqrtf(tot * (1.0f/512.0f) + 1e-6f);
    }
    u16* dstb = (u16*)(ws + (w < 2 ? WS_Q : WS_K));
    // fold 1/sqrt(64) AND log2(e) into Q so attention uses exp2 with no extra mult
    float qs = (w < 2) ? 0.125f*1.44269504f : 1.0f;
    #pragma unroll
    for (int f=0; f<8; f++){
      int jj = (j0 + f*16 + c) & 255;      // col within Q or K half
      int head = jj >> 6, dd = (jj & 63) + dOff;
      #pragma unroll
      for (int i=0;i<4;i++){
        int r = rb + q*4 + i;
        int b_ = r >> 11, n = r & 2047;
        dstb[((b_*4 + head)*2048 + n)*128 + dd] = f2bf(acc[f][i]*rmsr[i]*rsv[f]*qs);
      }
    }
  } else {
    int vb2 = bid - 1024;
    bool csd = vb2 >= 256;
    int rb = (vb2 & 255) * 32;
    const float* A   = csd ? C : V;
    int K            = csd ? 64 : 256;
    const float2* st = (const float2*)(ws + (csd ? WS_STATSC : WS_STATSV));
    const float* g   = csd ? cgam : vg;
    const float* bb  = csd ? cbet : vb;
    const u16* Wt    = (const u16*)(ws + (csd ? WS_WT_CV : WS_WT_VV));
    const float* bias= csd ? bcv : bvv;
    int dOff         = csd ? 64 : 0;

    int s = w & 1, cgp = w >> 1;       // 2 slabs x 2 colgroups(128)
    int r0 = rb + s*16, row = r0 + c;
    float2 stt = st[row];
    int j0 = cgp * 128;

    f32x4 acc[8];
    #pragma unroll
    for (int f=0; f<8; f++){ f32x4 z = {0.f,0.f,0.f,0.f}; acc[f] = z; }

    int nkc = K >> 5;
    for (int kc=0; kc<nkc; kc++){
      int k0 = kc*32 + q*8;
      s16x8 af = ln_frag(A, g, bb, row*K, k0, stt);
      #pragma unroll
      for (int f=0; f<8; f++){
        s16x8 bfr = *(const s16x8*)(Wt + (j0 + f*16 + c)*K + k0);
        acc[f] = mfma16(af, bfr, acc[f]);
      }
    }
    u16* vt = (u16*)(ws + WS_VT);
    int r = r0 + q*4;
    int b_ = r >> 11, n = r & 2047;
    #pragma unroll
    for (int f=0; f<8; f++){
      int j = j0 + f*16 + c;
      float bv_ = bias[j];
      int head = j >> 6, dd = (j & 63) + dOff;
      ushort4 pk;
      pk.x = f2bf(acc[f][0] + bv_); pk.y = f2bf(acc[f][1] + bv_);
      pk.z = f2bf(acc[f][2] + bv_); pk.w = f2bf(acc[f][3] + bv_);
      *(ushort4*)(vt + ((b_*4 + head)*128 + dd)*2048 + n) = pk;
    }
  }
}

// ---------------- flash attention v3: 16 Q-rows/wave, 4 waves/block, grid 512.
// Changes vs v2 (228us baseline): __launch_bounds__(256,2) frees the VGPR budget
// (occupancy is grid-limited at 2 waves/SIMD -> up to 256 VGPR/wave is free),
// global_load_lds DMA staging (source already pre-swizzled; LDS dest is linear
// uniform-base+lane*16 as required), 2x-unrolled t-loop for compile-time buffer idx.
__global__ __launch_bounds__(256, 2) void k_attn(char* ws){
  const u16* Qw = (const u16*)(ws + WS_Q);
  const u16* Kw = (const u16*)(ws + WS_K);
  const u16* Vt = (const u16*)(ws + WS_VT);
  u16* Ov = (u16*)(ws + WS_OV);
  u16* Oc = (u16*)(ws + WS_OC);
  __shared__ u16 Ks[2][4096];   // 2 bufs x 512 chunks x 8 (32 rows x 128 d)
  __shared__ u16 Vs[2][4096];   // 2 bufs x 512 chunks (128 d x 32 n)
  __shared__ u16 Ps[4][640];    // per-wave 16 x 40 (stride-40: ~2-way banks)

  int bh = blockIdx.x & 15, qb = blockIdx.x >> 4;
  int tid = threadIdx.x, lane = tid & 63, w = tid >> 6;
  int c = lane & 15, q = lane >> 4;
  int qr0 = qb*64 + w*16;

  // Q fragments direct from global (read-once); A-layout rows qr0+c
  s16x8 qf[4];
  #pragma unroll
  for (int kc=0;kc<4;kc++)
    qf[kc] = *(const s16x8*)(Qw + (bh*2048 + qr0 + c)*128 + kc*32 + q*8);

  // per-thread staging sources: chunk s = i*256 + tid; XOR pre-swizzle on (r,j).
  // LDS dest stays linear: chunk (i*256+tid)*8 -> byte = uniform + lane*16 (DMA-compatible).
  const u16 *ksrc0, *ksrc1, *vsrc0, *vsrc1;
  { int s0 = tid, s1 = 256 + tid;
    { int r = s0 >> 4, j = (s0 & 15) ^ (r & 15);      ksrc0 = Kw + (bh*2048 + r)*128 + j*8; }
    { int r = s1 >> 4, j = (s1 & 15) ^ (r & 15);      ksrc1 = Kw + (bh*2048 + r)*128 + j*8; }
    { int r = s0 >> 2, j = (s0 & 3) ^ ((r >> 1) & 3); vsrc0 = Vt + (bh*128 + r)*2048 + j*8; }
    { int r = s1 >> 2, j = (s1 & 3) ^ ((r >> 1) & 3); vsrc1 = Vt + (bh*128 + r)*2048 + j*8; }
  }

  f32x4 o[8];
  float lsum[4] = {0.f,0.f,0.f,0.f};
  #pragma unroll
  for (int f8=0;f8<8;f8++){ f32x4 z = {0.f,0.f,0.f,0.f}; o[f8] = z; }

  // stage tile t into buffer buf (async DMA; drained by the vmcnt(0) at the
  // compiler-emitted barrier wait of the next __syncthreads()).
  auto stage = [&](int buf, int t){
    async16(ksrc0 + t*4096, &Ks[buf][tid*8]);          // K tile stride: 32 rows * 128
    async16(ksrc1 + t*4096, &Ks[buf][(256+tid)*8]);
    async16(vsrc0 + t*32,   &Vs[buf][tid*8]);          // V tile stride: 32 cols
    async16(vsrc1 + t*32,   &Vs[buf][(256+tid)*8]);
  };

  auto step = [&](int bi, int t){
    __syncthreads();                 // buf bi staged & visible to all waves
    if (t < 63) stage(bi^1, t+1);    // issue next-tile DMA; lands before next barrier

    // K fragments: row f*16+c, chunk kc*4+q, swizzle ^c
    s16x8 kf[2][4];
    #pragma unroll
    for (int f=0;f<2;f++)
      #pragma unroll
      for (int kc=0;kc<4;kc++)
        kf[f][kc] = *(const s16x8*)(&Ks[bi][((f*16+c)*16 + (((kc*4+q) ^ c) & 15))*8]);
    // V fragments: row f8*16+c, chunk q, swizzle ^((c>>1)&3)
    s16x8 vf[8];
    #pragma unroll
    for (int f8=0;f8<8;f8++)
      vf[f8] = *(const s16x8*)(&Vs[bi][((f8*16+c)*4 + ((q ^ ((c>>1)&3)) & 3))*8]);

    // QK^T (Q pre-scaled by log2e/8)
    f32x4 sfr[2];
    #pragma unroll
    for (int f=0;f<2;f++){ f32x4 z = {0.f,0.f,0.f,0.f}; sfr[f] = z; }
    #pragma unroll
    for (int f=0;f<2;f++)
      #pragma unroll
      for (int kc=0;kc<4;kc++)
        sfr[f] = mfma16(qf[kc], kf[f][kc], sfr[f]);

    // p = exp2(s); no max subtraction (scores bounded; scale folded into Q)
    #pragma unroll
    for (int f=0;f<2;f++){
      #pragma unroll
      for (int i=0;i<4;i++){
        float p = exp2f(sfr[f][i]);
        lsum[i] += p;
        Ps[w][(q*4 + i)*40 + f*16 + c] = f2bf(p);
      }
    }
    // per-wave LDS round-trip: C-layout -> A-layout (no barrier needed)
    s16x8 pf = *(const s16x8*)(&Ps[w][c*40 + q*8]);
    #pragma unroll
    for (int f8=0;f8<8;f8++)
      o[f8] = mfma16(pf, vf[f8], o[f8]);
  };

  stage(0, 0);                       // prologue: tile 0 -> buf 0
  for (int t=0; t<64; t+=2){
    step(0, t);
    step(1, t+1);
  }

  #pragma unroll
  for (int d=1; d<16; d<<=1)
    #pragma unroll
    for (int i=0;i<4;i++) lsum[i] += __shfl_xor(lsum[i], d);
  float inv[4];
  #pragma unroll
  for (int i=0;i<4;i++) inv[i] = 1.0f/lsum[i];

  int b_ = bh >> 2, h = bh & 3;
  #pragma unroll
  for (int f8=0;f8<8;f8++){
    int col = f8*16 + c;
    u16* dst = (col < 64) ? Ov : Oc;
    int dd = col & 63;
    #pragma unroll
    for (int i=0;i<4;i++){
      int n = qr0 + q*4 + i;
      dst[(b_*2048 + n)*256 + h*64 + dd] = f2bf(o[f8][i]*inv[i]);
    }
  }
}

// ---------------- fused output projections v2 (more waves):
// bids [0,512) N=256 16-row blocks (4 waves x 64-col groups); [512,640) N=64 64-row blocks.
__global__ __launch_bounds__(256) void k_out(const u16* Av, const u16* Wtv, const float* bv,
                                             const u16* Ac, const u16* Wtc, const float* bc,
                                             float* out){
  int bid = blockIdx.x;
  int tid = threadIdx.x, lane = tid & 63, w = tid >> 6;
  int c = lane & 15, q = lane >> 4;
  if (bid < 512){
    int rb = bid * 16;
    int row = rb + c;
    int j0 = w * 64;
    f32x4 acc[4];
    #pragma unroll
    for (int f=0; f<4; f++){ f32x4 z = {0.f,0.f,0.f,0.f}; acc[f] = z; }
    for (int kc=0; kc<8; kc++){
      int k0 = kc*32 + q*8;
      s16x8 af = *(const s16x8*)(Av + row*256 + k0);
      #pragma unroll
      for (int f=0; f<4; f++){
        s16x8 bfr = *(const s16x8*)(Wtv + (j0 + f*16 + c)*256 + k0);
        acc[f] = mfma16(af, bfr, acc[f]);
      }
    }
    #pragma unroll
    for (int f=0; f<4; f++){
      int j = j0 + f*16 + c;
      float bb = bv[j];
      #pragma unroll
      for (int i=0;i<4;i++)
        out[(rb + q*4 + i)*256 + j] = acc[f][i] + bb;
    }
  } else {
    int rb = (bid - 512) * 64;
    int r0 = rb + w*16, row = r0 + c;
    f32x4 acc[4];
    #pragma unroll
    for (int f=0; f<4; f++){ f32x4 z = {0.f,0.f,0.f,0.f}; acc[f] = z; }
    for (int kc=0; kc<8; kc++){
      int k0 = kc*32 + q*8;
      s16x8 af = *(const s16x8*)(Ac + row*256 + k0);
      #pragma unroll
      for (int f=0; f<4; f++){
        s16x8 bfr = *(const s16x8*)(Wtc + (f*16 + c)*256 + k0);
        acc[f] = mfma16(af, bfr, acc[f]);
      }
    }
    float* oc = out + 2097152;
    #pragma unroll
    for (int f=0; f<4; f++){
      int j = f*16 + c;
      float bb = bc[j];
      #pragma unroll
      for (int i=0;i<4;i++)
        oc[(r0 + q*4 + i)*64 + j] = acc[f][i] + bb;
    }
  }
}

extern "C" void kernel_launch(void* const* d_in, const int* in_sizes, int n_in,
                              void* d_out, int out_size, void* d_ws, size_t ws_size,
                              hipStream_t stream){
  (void)in_sizes; (void)n_in; (void)out_size; (void)ws_size;
  const float* V    = (const float*)d_in[0];
  const float* C    = (const float*)d_in[1];
  const float* vng  = (const float*)d_in[2];
  const float* vnb  = (const float*)d_in[3];
  const float* cng  = (const float*)d_in[4];
  const float* cnb  = (const float*)d_in[5];
  const float* Wvqk = (const float*)d_in[6];
  const float* bvqk = (const float*)d_in[7];
  const float* rmsv = (const float*)d_in[8];
  const float* Wcqk = (const float*)d_in[9];
  const float* bcqk = (const float*)d_in[10];
  const float* rmsc = (const float*)d_in[11];
  const float* Wvv  = (const float*)d_in[12];
  const float* bvv  = (const float*)d_in[13];
  const float* Wcv  = (const float*)d_in[14];
  const float* bcv  = (const float*)d_in[15];
  const float* Wov  = (const float*)d_in[16];
  const float* bov  = (const float*)d_in[17];
  const float* Woc  = (const float*)d_in[18];
  const float* boc  = (const float*)d_in[19];
  char* ws = (char*)d_ws;
  float* out = (float*)d_out;

  k_prep<<<4256, 256, 0, stream>>>(V, C, Wvqk, Wcqk, Wvv, Wcv, Wov, Woc, ws);
  k_proj<<<1536, 256, 0, stream>>>(V, C, vng, vnb, cng, cnb,
                                   bvqk, bcqk, rmsv, rmsc, bvv, bcv, ws);
  k_attn<<<512, 256, 0, stream>>>(ws);
  k_out<<<640, 256, 0, stream>>>((const u16*)(ws + WS_OV), (const u16*)(ws + WS_WT_OV), bov,
                                 (const u16*)(ws + WS_OC), (const u16*)(ws + WS_WT_OC), boc,
                                 out);
}

// Round 2
// 219.267 us; speedup vs baseline: 1.0428x; 1.0295x over previous
//
#include <hip/hip_runtime.h>

typedef unsigned short u16;
typedef unsigned int   u32;
typedef short s16x8 __attribute__((ext_vector_type(8)));   // 8 x bf16 (4 VGPRs)
typedef float f32x4 __attribute__((ext_vector_type(4)));

// ---- workspace layout (bytes); total footprint 34,340,864 (proven safe) ----
#define WS_STATSV 0          // 8192 * float2
#define WS_STATSC 65536      // 8192 * float2
#define WS_WT_VQK 131072     // [512][256] bf16
#define WS_WT_CQK 393216     // [512][64]
#define WS_WT_VV  458752     // [256][256]
#define WS_WT_CV  589824     // [256][64]
#define WS_WT_OV  622592     // [256][256]
#define WS_WT_OC  753664     // [64][256]
#define WS_Q      786432     // [16][2048][128] bf16  (qv|qc per head; Q pre-scaled by log2e/8)
#define WS_K      9175040    // [16][2048][128] bf16
#define WS_VT     17563648   // [16][128][2048] bf16 (V^T per bh; d: vv 0..63, vc 64..127)
#define WS_OV     25952256   // [8192][256] bf16
#define WS_OC     30146560   // [8192][256] bf16  (ends 34,340,864)

__device__ __forceinline__ float bf2f(u16 h){
  union { u32 u; float f; } x; x.u = ((u32)h) << 16; return x.f;
}
__device__ __forceinline__ u16 f2bf(float f){
  union { float f; u32 u; } x; x.f = f;
  u32 u = x.u; u += 0x7fffu + ((u >> 16) & 1u);
  return (u16)(u >> 16);
}
__device__ __forceinline__ f32x4 mfma16(s16x8 a, s16x8 b, f32x4 c){
  return __builtin_amdgcn_mfma_f32_16x16x32_bf16(a, b, c, 0, 0, 0);
}
// async global->LDS DMA, 16B per lane; LDS dest must be uniform-base + lane*16 (it is).
__device__ __forceinline__ void async16(const u16* g, u16* l){
  __builtin_amdgcn_global_load_lds(
      (const __attribute__((address_space(1))) u32*)(const void*)g,
      (__attribute__((address_space(3))) u32*)(void*)l, 16, 0, 0);
}

// ---------------- fused: LN row stats (bids 0..4095) + weight transpose (4096..4255) ----------------
__global__ __launch_bounds__(256) void k_prep(const float* V, const float* C,
    const float* Wvqk, const float* Wcqk, const float* Wvv, const float* Wcv,
    const float* Wov, const float* Woc, char* ws){
  int bid = blockIdx.x;
  if (bid < 4096){
    int wid = threadIdx.x >> 6, lane = threadIdx.x & 63;
    float2* sV = (float2*)(ws + WS_STATSV);
    float2* sC = (float2*)(ws + WS_STATSC);
    float s = 0.f, s2 = 0.f; int row; float2* dst; float invn;
    if (bid < 2048){
      row = bid*4 + wid;
      const float4* p = (const float4*)(V + row*256);
      float4 v = p[lane];
      s = v.x+v.y+v.z+v.w; s2 = v.x*v.x+v.y*v.y+v.z*v.z+v.w*v.w;
      dst = sV; invn = 1.0f/256.0f;
    } else {
      row = (bid-2048)*4 + wid;
      float x = C[row*64 + lane];
      s = x; s2 = x*x;
      dst = sC; invn = 1.0f/64.0f;
    }
    for (int d=1; d<64; d<<=1){ s += __shfl_xor(s,d); s2 += __shfl_xor(s2,d); }
    if (lane == 0){
      float m = s*invn; float var = s2*invn - m*m; if (var < 0.f) var = 0.f;
      float rstd = rsqrtf(var + 1e-5f);
      float2 o; o.x = rstd; o.y = -m*rstd;
      dst[row] = o;
    }
  } else {
    int tb = bid - 4096;
    const float* src; u16* dst; int K, N, rel;
    if      (tb <  64){ src=Wvqk; dst=(u16*)(ws+WS_WT_VQK); K=256; N=512; rel=tb;     }
    else if (tb <  80){ src=Wcqk; dst=(u16*)(ws+WS_WT_CQK); K=64;  N=512; rel=tb-64;  }
    else if (tb < 112){ src=Wvv;  dst=(u16*)(ws+WS_WT_VV);  K=256; N=256; rel=tb-80;  }
    else if (tb < 120){ src=Wcv;  dst=(u16*)(ws+WS_WT_CV);  K=64;  N=256; rel=tb-112; }
    else if (tb < 152){ src=Wov;  dst=(u16*)(ws+WS_WT_OV);  K=256; N=256; rel=tb-120; }
    else              { src=Woc;  dst=(u16*)(ws+WS_WT_OC);  K=256; N=64;  rel=tb-152; }
    int e = rel*2048 + threadIdx.x*8;
    int k = e / N, n0 = e % N;
    float4 t0 = *(const float4*)(src + e);
    float4 t1 = *(const float4*)(src + e + 4);
    dst[(n0+0)*K + k] = f2bf(t0.x);
    dst[(n0+1)*K + k] = f2bf(t0.y);
    dst[(n0+2)*K + k] = f2bf(t0.z);
    dst[(n0+3)*K + k] = f2bf(t0.w);
    dst[(n0+4)*K + k] = f2bf(t1.x);
    dst[(n0+5)*K + k] = f2bf(t1.y);
    dst[(n0+6)*K + k] = f2bf(t1.z);
    dst[(n0+7)*K + k] = f2bf(t1.w);
  }
}

__device__ __forceinline__ s16x8 ln_frag(const float* A, const float* g, const float* bb,
                                         int base, int k0, float2 stt){
  float4 x0 = *(const float4*)(A + base + k0);
  float4 x1 = *(const float4*)(A + base + k0 + 4);
  float4 g0 = *(const float4*)(g + k0);
  float4 g1 = *(const float4*)(g + k0 + 4);
  float4 b0 = *(const float4*)(bb + k0);
  float4 b1 = *(const float4*)(bb + k0 + 4);
  s16x8 af;
  af[0] = (short)f2bf(fmaf(fmaf(x0.x, stt.x, stt.y), g0.x, b0.x));
  af[1] = (short)f2bf(fmaf(fmaf(x0.y, stt.x, stt.y), g0.y, b0.y));
  af[2] = (short)f2bf(fmaf(fmaf(x0.z, stt.x, stt.y), g0.z, b0.z));
  af[3] = (short)f2bf(fmaf(fmaf(x0.w, stt.x, stt.y), g0.w, b0.w));
  af[4] = (short)f2bf(fmaf(fmaf(x1.x, stt.x, stt.y), g1.x, b1.x));
  af[5] = (short)f2bf(fmaf(fmaf(x1.y, stt.x, stt.y), g1.y, b1.y));
  af[6] = (short)f2bf(fmaf(fmaf(x1.z, stt.x, stt.y), g1.z, b1.z));
  af[7] = (short)f2bf(fmaf(fmaf(x1.w, stt.x, stt.y), g1.w, b1.w));
  return af;
}

// ---------------- fused projections v2 (more waves):
// bids [0,512) V-qk 16-row, [512,1024) C-qk 16-row, [1024,1280) V-v 32-row, [1280,1536) C-v 32-row
__global__ __launch_bounds__(256) void k_proj(const float* V, const float* C,
    const float* vg, const float* vb, const float* cgam, const float* cbet,
    const float* bvqk, const float* bcqk, const float* rmsv, const float* rmsc,
    const float* bvv, const float* bcv, char* ws){
  __shared__ float ssl[4][16];
  int bid = blockIdx.x;
  int tid = threadIdx.x, lane = tid & 63, w = tid >> 6;
  int c = lane & 15, q = lane >> 4;

  if (bid < 1024){
    bool csd = bid >= 512;
    int rb = (bid & 511) * 16;
    const float* A   = csd ? C : V;
    int K            = csd ? 64 : 256;
    const float2* st = (const float2*)(ws + (csd ? WS_STATSC : WS_STATSV));
    const float* g   = csd ? cgam : vg;
    const float* bb  = csd ? cbet : vb;
    const u16* Wt    = (const u16*)(ws + (csd ? WS_WT_CQK : WS_WT_VQK));
    const float* bias= csd ? bcqk : bvqk;
    const float* rms = csd ? rmsc : rmsv;
    int dOff         = csd ? 64 : 0;

    int row = rb + c;
    float2 stt = st[row];
    int j0 = w * 128;                 // wave = 128-col group of the 512

    f32x4 acc[8];
    #pragma unroll
    for (int f=0; f<8; f++){ f32x4 z = {0.f,0.f,0.f,0.f}; acc[f] = z; }

    int nkc = K >> 5;
    for (int kc=0; kc<nkc; kc++){
      int k0 = kc*32 + q*8;
      s16x8 af = ln_frag(A, g, bb, row*K, k0, stt);
      #pragma unroll
      for (int f=0; f<8; f++){
        s16x8 bfr = *(const s16x8*)(Wt + (j0 + f*16 + c)*K + k0);
        acc[f] = mfma16(af, bfr, acc[f]);
      }
    }

    float ss[4] = {0.f,0.f,0.f,0.f};
    float rsv[8];
    #pragma unroll
    for (int f=0; f<8; f++){
      int j = j0 + f*16 + c;
      float bsv = bias[j]; rsv[f] = rms[j];
      #pragma unroll
      for (int i=0;i<4;i++){ acc[f][i] += bsv; ss[i] += acc[f][i]*acc[f][i]; }
    }
    #pragma unroll
    for (int d=1; d<16; d<<=1){
      #pragma unroll
      for (int i=0;i<4;i++) ss[i] += __shfl_xor(ss[i], d);
    }
    if (c == 0){
      #pragma unroll
      for (int i=0;i<4;i++) ssl[w][q*4 + i] = ss[i];
    }
    __syncthreads();
    float rmsr[4];
    #pragma unroll
    for (int i=0;i<4;i++){
      int rl = q*4 + i;
      float tot = ssl[0][rl] + ssl[1][rl] + ssl[2][rl] + ssl[3][rl];
      rmsr[i] = rsqrtf(tot * (1.0f/512.0f) + 1e-6f);
    }
    u16* dstb = (u16*)(ws + (w < 2 ? WS_Q : WS_K));
    // fold 1/sqrt(64) AND log2(e) into Q so attention uses exp2 with no extra mult
    float qs = (w < 2) ? 0.125f*1.44269504f : 1.0f;
    #pragma unroll
    for (int f=0; f<8; f++){
      int jj = (j0 + f*16 + c) & 255;      // col within Q or K half
      int head = jj >> 6, dd = (jj & 63) + dOff;
      #pragma unroll
      for (int i=0;i<4;i++){
        int r = rb + q*4 + i;
        int b_ = r >> 11, n = r & 2047;
        dstb[((b_*4 + head)*2048 + n)*128 + dd] = f2bf(acc[f][i]*rmsr[i]*rsv[f]*qs);
      }
    }
  } else {
    int vb2 = bid - 1024;
    bool csd = vb2 >= 256;
    int rb = (vb2 & 255) * 32;
    const float* A   = csd ? C : V;
    int K            = csd ? 64 : 256;
    const float2* st = (const float2*)(ws + (csd ? WS_STATSC : WS_STATSV));
    const float* g   = csd ? cgam : vg;
    const float* bb  = csd ? cbet : vb;
    const u16* Wt    = (const u16*)(ws + (csd ? WS_WT_CV : WS_WT_VV));
    const float* bias= csd ? bcv : bvv;
    int dOff         = csd ? 64 : 0;

    int s = w & 1, cgp = w >> 1;       // 2 slabs x 2 colgroups(128)
    int r0 = rb + s*16, row = r0 + c;
    float2 stt = st[row];
    int j0 = cgp * 128;

    f32x4 acc[8];
    #pragma unroll
    for (int f=0; f<8; f++){ f32x4 z = {0.f,0.f,0.f,0.f}; acc[f] = z; }

    int nkc = K >> 5;
    for (int kc=0; kc<nkc; kc++){
      int k0 = kc*32 + q*8;
      s16x8 af = ln_frag(A, g, bb, row*K, k0, stt);
      #pragma unroll
      for (int f=0; f<8; f++){
        s16x8 bfr = *(const s16x8*)(Wt + (j0 + f*16 + c)*K + k0);
        acc[f] = mfma16(af, bfr, acc[f]);
      }
    }
    u16* vt = (u16*)(ws + WS_VT);
    int r = r0 + q*4;
    int b_ = r >> 11, n = r & 2047;
    #pragma unroll
    for (int f=0; f<8; f++){
      int j = j0 + f*16 + c;
      float bv_ = bias[j];
      int head = j >> 6, dd = (j & 63) + dOff;
      ushort4 pk;
      pk.x = f2bf(acc[f][0] + bv_); pk.y = f2bf(acc[f][1] + bv_);
      pk.z = f2bf(acc[f][2] + bv_); pk.w = f2bf(acc[f][3] + bv_);
      *(ushort4*)(vt + ((b_*4 + head)*128 + dd)*2048 + n) = pk;
    }
  }
}

// ---------------- flash attention v4: KV-split within block.
// 512 blocks x 4 waves. Wave (g,h): g = Q-subblock (32 rows as 2x16), h = KV half (32 tiles).
// Rationale (round-1 counters): LDS-read issue was ~62% of kernel cycles (17 ds_read_b128
// per wave per tile serving only 16 MFMA). Amortizing kf/vf over TWO 16-row Q-subgroups
// halves LDS reads per FLOP (18 reads -> 32 MFMA); KV-split keeps the grid at 512.
// f32 partials (o, lsum) merged through LDS at the end — no precision loss, no extra WS.
__global__ __launch_bounds__(256, 2) void k_attn(char* ws){
  const u16* Qw = (const u16*)(ws + WS_Q);
  const u16* Kw = (const u16*)(ws + WS_K);
  const u16* Vt = (const u16*)(ws + WS_VT);
  u16* Ov = (u16*)(ws + WS_OV);
  u16* Oc = (u16*)(ws + WS_OC);
  // smem map (bytes): K stages [4][8192] at 0; V stages [4][8192] at 32768;
  // Ps [4 waves][2 sub][1280B] at 65536. Total 75776. Merge overlays bytes [0,37376).
  __shared__ char smem[75776];
  u16* sm16 = (u16*)smem;

  int bh = blockIdx.x & 15, qb = blockIdx.x >> 4;
  int tid = threadIdx.x, lane = tid & 63, w = tid >> 6;
  int c = lane & 15, q = lane >> 4;
  int g = w & 1, h = w >> 1, ht = tid & 127;
  int qr0 = qb*64 + g*32;

  // Q fragments (A-layout rows qr0 + s*16 + c), read-once from global
  s16x8 qf[2][4];
  #pragma unroll
  for (int s=0;s<2;s++)
    #pragma unroll
    for (int kc=0;kc<4;kc++)
      qf[s][kc] = *(const s16x8*)(Qw + (bh*2048 + qr0 + s*16 + c)*128 + kc*32 + q*8);

  // staging sources for this thread's half: chunk s = i*128 + ht, XOR pre-swizzle.
  const u16* ksrc[4]; const u16* vsrc[4];
  #pragma unroll
  for (int i=0;i<4;i++){
    int sc = i*128 + ht;
    { int r = sc >> 4, j = (sc & 15) ^ (r & 15);        // K: 32 rows x 16 chunks
      ksrc[i] = Kw + (bh*2048 + r)*128 + j*8; }
    { int r = sc >> 2, j = (sc & 3) ^ ((r >> 1) & 3);   // V: 128 rows x 4 chunks
      vsrc[i] = Vt + (bh*128 + r)*2048 + j*8; }
  }

  f32x4 o[2][8];
  float lsum[2][4];
  #pragma unroll
  for (int s=0;s<2;s++){
    #pragma unroll
    for (int f8=0;f8<8;f8++){ f32x4 z = {0.f,0.f,0.f,0.f}; o[s][f8] = z; }
    #pragma unroll
    for (int i=0;i<4;i++) lsum[s][i] = 0.f;
  }

  // stage tile t (absolute) into this half's buffer buf via async DMA (linear LDS dest).
  auto stage = [&](int buf, int t){
    u16* kd = sm16 + (h*2+buf)*4096;
    u16* vd = sm16 + 16384 + (h*2+buf)*4096;
    #pragma unroll
    for (int i=0;i<4;i++){
      async16(ksrc[i] + t*4096, kd + (i*128+ht)*8);   // K tile stride: 32 rows * 128
      async16(vsrc[i] + t*32,   vd + (i*128+ht)*8);   // V tile stride: 32 cols
    }
  };

  auto step = [&](int bi, int tt){
    int t = h*32 + tt;
    __syncthreads();                 // this half's buf bi staged (vmcnt(0) drained here)
    if (tt < 31) stage(bi^1, t+1);   // issue next-tile DMA; lands before next barrier

    const u16* kb = sm16 + (h*2+bi)*4096;
    const u16* vb = sm16 + 16384 + (h*2+bi)*4096;
    // K fragments: row f*16+c, chunk kc*4+q, swizzle ^c — shared by both Q-subgroups
    s16x8 kf[2][4];
    #pragma unroll
    for (int f=0;f<2;f++)
      #pragma unroll
      for (int kc=0;kc<4;kc++)
        kf[f][kc] = *(const s16x8*)(kb + ((f*16+c)*16 + (((kc*4+q) ^ c) & 15))*8);
    // V fragments: row f8*16+c, chunk q, swizzle ^((c>>1)&3)
    s16x8 vf[8];
    #pragma unroll
    for (int f8=0;f8<8;f8++)
      vf[f8] = *(const s16x8*)(vb + ((f8*16+c)*4 + ((q ^ ((c>>1)&3)) & 3))*8);

    // QK^T for both subgroups (Q pre-scaled by log2e/8)
    f32x4 sfr[2][2];
    #pragma unroll
    for (int s=0;s<2;s++)
      #pragma unroll
      for (int f=0;f<2;f++){ f32x4 z = {0.f,0.f,0.f,0.f}; sfr[s][f] = z; }
    #pragma unroll
    for (int s=0;s<2;s++)
      #pragma unroll
      for (int f=0;f<2;f++)
        #pragma unroll
        for (int kc=0;kc<4;kc++)
          sfr[s][f] = mfma16(qf[s][kc], kf[f][kc], sfr[s][f]);

    // softmax numerator + PV, per subgroup (separate Ps regions allow overlap)
    #pragma unroll
    for (int s=0;s<2;s++){
      u16* ps = sm16 + 32768 + (w*2+s)*640;
      #pragma unroll
      for (int f=0;f<2;f++){
        #pragma unroll
        for (int i=0;i<4;i++){
          float p = exp2f(sfr[s][f][i]);
          lsum[s][i] += p;
          ps[(q*4 + i)*40 + f*16 + c] = f2bf(p);
        }
      }
      s16x8 pf = *(const s16x8*)(ps + c*40 + q*8);   // per-wave bounce, no barrier
      #pragma unroll
      for (int f8=0;f8<8;f8++)
        o[s][f8] = mfma16(pf, vf[f8], o[s][f8]);
    }
  };

  stage(0, h*32);                    // prologue: this half's first tile -> buf 0
  for (int tt=0; tt<32; tt+=2){
    step(0, tt);
    step(1, tt+1);
  }

  // ---- merge the two KV halves (f32, via LDS) ----
  __syncthreads();                   // all tile compute done; staging buffers free
  float* mg = (float*)smem;          // [2 g][64 lane] x 73 floats (stride 73: conflict-free)
  if (h == 1){
    float* d = mg + (g*64 + lane)*73;
    #pragma unroll
    for (int s=0;s<2;s++)
      #pragma unroll
      for (int f8=0;f8<8;f8++)
        #pragma unroll
        for (int i=0;i<4;i++) d[(s*8+f8)*4 + i] = o[s][f8][i];
    #pragma unroll
    for (int s=0;s<2;s++)
      #pragma unroll
      for (int i=0;i<4;i++) d[64 + s*4 + i] = lsum[s][i];
  }
  __syncthreads();
  if (h == 0){
    float* d = mg + (g*64 + lane)*73;
    #pragma unroll
    for (int s=0;s<2;s++)
      #pragma unroll
      for (int f8=0;f8<8;f8++)
        #pragma unroll
        for (int i=0;i<4;i++) o[s][f8][i] += d[(s*8+f8)*4 + i];
    #pragma unroll
    for (int s=0;s<2;s++)
      #pragma unroll
      for (int i=0;i<4;i++) lsum[s][i] += d[64 + s*4 + i];

    #pragma unroll
    for (int dd=1; dd<16; dd<<=1)
      #pragma unroll
      for (int s=0;s<2;s++)
        #pragma unroll
        for (int i=0;i<4;i++) lsum[s][i] += __shfl_xor(lsum[s][i], dd);

    int b_ = bh >> 2, hh = bh & 3;
    #pragma unroll
    for (int s=0;s<2;s++){
      float inv[4];
      #pragma unroll
      for (int i=0;i<4;i++) inv[i] = 1.0f/lsum[s][i];
      #pragma unroll
      for (int f8=0;f8<8;f8++){
        int col = f8*16 + c;
        u16* dst = (col < 64) ? Ov : Oc;
        int ddim = col & 63;
        #pragma unroll
        for (int i=0;i<4;i++){
          int n = qr0 + s*16 + q*4 + i;
          dst[(b_*2048 + n)*256 + hh*64 + ddim] = f2bf(o[s][f8][i]*inv[i]);
        }
      }
    }
  }
}

// ---------------- fused output projections v2 (more waves):
// bids [0,512) N=256 16-row blocks (4 waves x 64-col groups); [512,640) N=64 64-row blocks.
__global__ __launch_bounds__(256) void k_out(const u16* Av, const u16* Wtv, const float* bv,
                                             const u16* Ac, const u16* Wtc, const float* bc,
                                             float* out){
  int bid = blockIdx.x;
  int tid = threadIdx.x, lane = tid & 63, w = tid >> 6;
  int c = lane & 15, q = lane >> 4;
  if (bid < 512){
    int rb = bid * 16;
    int row = rb + c;
    int j0 = w * 64;
    f32x4 acc[4];
    #pragma unroll
    for (int f=0; f<4; f++){ f32x4 z = {0.f,0.f,0.f,0.f}; acc[f] = z; }
    for (int kc=0; kc<8; kc++){
      int k0 = kc*32 + q*8;
      s16x8 af = *(const s16x8*)(Av + row*256 + k0);
      #pragma unroll
      for (int f=0; f<4; f++){
        s16x8 bfr = *(const s16x8*)(Wtv + (j0 + f*16 + c)*256 + k0);
        acc[f] = mfma16(af, bfr, acc[f]);
      }
    }
    #pragma unroll
    for (int f=0; f<4; f++){
      int j = j0 + f*16 + c;
      float bb = bv[j];
      #pragma unroll
      for (int i=0;i<4;i++)
        out[(rb + q*4 + i)*256 + j] = acc[f][i] + bb;
    }
  } else {
    int rb = (bid - 512) * 64;
    int r0 = rb + w*16, row = r0 + c;
    f32x4 acc[4];
    #pragma unroll
    for (int f=0; f<4; f++){ f32x4 z = {0.f,0.f,0.f,0.f}; acc[f] = z; }
    for (int kc=0; kc<8; kc++){
      int k0 = kc*32 + q*8;
      s16x8 af = *(const s16x8*)(Ac + row*256 + k0);
      #pragma unroll
      for (int f=0; f<4; f++){
        s16x8 bfr = *(const s16x8*)(Wtc + (f*16 + c)*256 + k0);
        acc[f] = mfma16(af, bfr, acc[f]);
      }
    }
    float* oc = out + 2097152;
    #pragma unroll
    for (int f=0; f<4; f++){
      int j = f*16 + c;
      float bb = bc[j];
      #pragma unroll
      for (int i=0;i<4;i++)
        oc[(r0 + q*4 + i)*64 + j] = acc[f][i] + bb;
    }
  }
}

extern "C" void kernel_launch(void* const* d_in, const int* in_sizes, int n_in,
                              void* d_out, int out_size, void* d_ws, size_t ws_size,
                              hipStream_t stream){
  (void)in_sizes; (void)n_in; (void)out_size; (void)ws_size;
  const float* V    = (const float*)d_in[0];
  const float* C    = (const float*)d_in[1];
  const float* vng  = (const float*)d_in[2];
  const float* vnb  = (const float*)d_in[3];
  const float* cng  = (const float*)d_in[4];
  const float* cnb  = (const float*)d_in[5];
  const float* Wvqk = (const float*)d_in[6];
  const float* bvqk = (const float*)d_in[7];
  const float* rmsv = (const float*)d_in[8];
  const float* Wcqk = (const float*)d_in[9];
  const float* bcqk = (const float*)d_in[10];
  const float* rmsc = (const float*)d_in[11];
  const float* Wvv  = (const float*)d_in[12];
  const float* bvv  = (const float*)d_in[13];
  const float* Wcv  = (const float*)d_in[14];
  const float* bcv  = (const float*)d_in[15];
  const float* Wov  = (const float*)d_in[16];
  const float* bov  = (const float*)d_in[17];
  const float* Woc  = (const float*)d_in[18];
  const float* boc  = (const float*)d_in[19];
  char* ws = (char*)d_ws;
  float* out = (float*)d_out;

  k_prep<<<4256, 256, 0, stream>>>(V, C, Wvqk, Wcqk, Wvv, Wcv, Wov, Woc, ws);
  k_proj<<<1536, 256, 0, stream>>>(V, C, vng, vnb, cng, cnb,
                                   bvqk, bcqk, rmsv, rmsc, bvv, bcv, ws);
  k_attn<<<512, 256, 0, stream>>>(ws);
  k_out<<<640, 256, 0, stream>>>((const u16*)(ws + WS_OV), (const u16*)(ws + WS_WT_OV), bov,
                                 (const u16*)(ws + WS_OC), (const u16*)(ws + WS_WT_OC), boc,
                                 out);
}

// Round 4
// 215.122 us; speedup vs baseline: 1.0629x; 1.0193x over previous
//
#include <hip/hip_runtime.h>

typedef unsigned short u16;
typedef unsigned int   u32;
typedef short s16x8 __attribute__((ext_vector_type(8)));   // 8 x bf16 (4 VGPRs)
typedef float f32x4 __attribute__((ext_vector_type(4)));

// ---- workspace layout (bytes); total footprint 34,340,864 (proven safe) ----
#define WS_STATSV 0          // 8192 * float2
#define WS_STATSC 65536      // 8192 * float2
#define WS_WT_VQK 131072     // [512][256] bf16
#define WS_WT_CQK 393216     // [512][64]
#define WS_WT_VV  458752     // [256][256]
#define WS_WT_CV  589824     // [256][64]
#define WS_WT_OV  622592     // [256][256]
#define WS_WT_OC  753664     // [64][256]
#define WS_Q      786432     // [16][2048][128] bf16  (qv|qc per head; Q pre-scaled by log2e/8)
#define WS_K      9175040    // [16][2048][128] bf16
#define WS_VT     17563648   // [16][128][2048] bf16 (V^T per bh; n permuted within 32-blocks, see k_proj)
#define WS_OV     25952256   // [8192][256] bf16
#define WS_OC     30146560   // [8192][256] bf16  (ends 34,340,864)

__device__ __forceinline__ float bf2f(u16 h){
  union { u32 u; float f; } x; x.u = ((u32)h) << 16; return x.f;
}
__device__ __forceinline__ u16 f2bf(float f){
  union { float f; u32 u; } x; x.f = f;
  u32 u = x.u; u += 0x7fffu + ((u >> 16) & 1u);
  return (u16)(u >> 16);
}
__device__ __forceinline__ f32x4 mfma16(s16x8 a, s16x8 b, f32x4 c){
  return __builtin_amdgcn_mfma_f32_16x16x32_bf16(a, b, c, 0, 0, 0);
}
// async global->LDS DMA, 16B per lane; LDS dest must be uniform-base + lane*16 (it is).
__device__ __forceinline__ void async16(const u16* g, u16* l){
  __builtin_amdgcn_global_load_lds(
      (const __attribute__((address_space(1))) u32*)(const void*)g,
      (__attribute__((address_space(3))) u32*)(void*)l, 16, 0, 0);
}

// ---------------- fused: LN row stats (bids 0..4095) + weight transpose (4096..4255) ----------------
__global__ __launch_bounds__(256) void k_prep(const float* V, const float* C,
    const float* Wvqk, const float* Wcqk, const float* Wvv, const float* Wcv,
    const float* Wov, const float* Woc, char* ws){
  int bid = blockIdx.x;
  if (bid < 4096){
    int wid = threadIdx.x >> 6, lane = threadIdx.x & 63;
    float2* sV = (float2*)(ws + WS_STATSV);
    float2* sC = (float2*)(ws + WS_STATSC);
    float s = 0.f, s2 = 0.f; int row; float2* dst; float invn;
    if (bid < 2048){
      row = bid*4 + wid;
      const float4* p = (const float4*)(V + row*256);
      float4 v = p[lane];
      s = v.x+v.y+v.z+v.w; s2 = v.x*v.x+v.y*v.y+v.z*v.z+v.w*v.w;
      dst = sV; invn = 1.0f/256.0f;
    } else {
      row = (bid-2048)*4 + wid;
      float x = C[row*64 + lane];
      s = x; s2 = x*x;
      dst = sC; invn = 1.0f/64.0f;
    }
    for (int d=1; d<64; d<<=1){ s += __shfl_xor(s,d); s2 += __shfl_xor(s2,d); }
    if (lane == 0){
      float m = s*invn; float var = s2*invn - m*m; if (var < 0.f) var = 0.f;
      float rstd = rsqrtf(var + 1e-5f);
      float2 o; o.x = rstd; o.y = -m*rstd;
      dst[row] = o;
    }
  } else {
    int tb = bid - 4096;
    const float* src; u16* dst; int K, N, rel;
    if      (tb <  64){ src=Wvqk; dst=(u16*)(ws+WS_WT_VQK); K=256; N=512; rel=tb;     }
    else if (tb <  80){ src=Wcqk; dst=(u16*)(ws+WS_WT_CQK); K=64;  N=512; rel=tb-64;  }
    else if (tb < 112){ src=Wvv;  dst=(u16*)(ws+WS_WT_VV);  K=256; N=256; rel=tb-80;  }
    else if (tb < 120){ src=Wcv;  dst=(u16*)(ws+WS_WT_CV);  K=64;  N=256; rel=tb-112; }
    else if (tb < 152){ src=Wov;  dst=(u16*)(ws+WS_WT_OV);  K=256; N=256; rel=tb-120; }
    else              { src=Woc;  dst=(u16*)(ws+WS_WT_OC);  K=256; N=64;  rel=tb-152; }
    int e = rel*2048 + threadIdx.x*8;
    int k = e / N, n0 = e % N;
    float4 t0 = *(const float4*)(src + e);
    float4 t1 = *(const float4*)(src + e + 4);
    dst[(n0+0)*K + k] = f2bf(t0.x);
    dst[(n0+1)*K + k] = f2bf(t0.y);
    dst[(n0+2)*K + k] = f2bf(t0.z);
    dst[(n0+3)*K + k] = f2bf(t0.w);
    dst[(n0+4)*K + k] = f2bf(t1.x);
    dst[(n0+5)*K + k] = f2bf(t1.y);
    dst[(n0+6)*K + k] = f2bf(t1.z);
    dst[(n0+7)*K + k] = f2bf(t1.w);
  }
}

__device__ __forceinline__ s16x8 ln_frag(const float* A, const float* g, const float* bb,
                                         int base, int k0, float2 stt){
  float4 x0 = *(const float4*)(A + base + k0);
  float4 x1 = *(const float4*)(A + base + k0 + 4);
  float4 g0 = *(const float4*)(g + k0);
  float4 g1 = *(const float4*)(g + k0 + 4);
  float4 b0 = *(const float4*)(bb + k0);
  float4 b1 = *(const float4*)(bb + k0 + 4);
  s16x8 af;
  af[0] = (short)f2bf(fmaf(fmaf(x0.x, stt.x, stt.y), g0.x, b0.x));
  af[1] = (short)f2bf(fmaf(fmaf(x0.y, stt.x, stt.y), g0.y, b0.y));
  af[2] = (short)f2bf(fmaf(fmaf(x0.z, stt.x, stt.y), g0.z, b0.z));
  af[3] = (short)f2bf(fmaf(fmaf(x0.w, stt.x, stt.y), g0.w, b0.w));
  af[4] = (short)f2bf(fmaf(fmaf(x1.x, stt.x, stt.y), g1.x, b1.x));
  af[5] = (short)f2bf(fmaf(fmaf(x1.y, stt.x, stt.y), g1.y, b1.y));
  af[6] = (short)f2bf(fmaf(fmaf(x1.z, stt.x, stt.y), g1.z, b1.z));
  af[7] = (short)f2bf(fmaf(fmaf(x1.w, stt.x, stt.y), g1.w, b1.w));
  return af;
}

// ---------------- fused projections v2 (more waves):
// bids [0,512) V-qk 16-row, [512,1024) C-qk 16-row, [1024,1280) V-v 32-row, [1280,1536) C-v 32-row
__global__ __launch_bounds__(256) void k_proj(const float* V, const float* C,
    const float* vg, const float* vb, const float* cgam, const float* cbet,
    const float* bvqk, const float* bcqk, const float* rmsv, const float* rmsc,
    const float* bvv, const float* bcv, char* ws){
  __shared__ float ssl[4][16];
  int bid = blockIdx.x;
  int tid = threadIdx.x, lane = tid & 63, w = tid >> 6;
  int c = lane & 15, q = lane >> 4;

  if (bid < 1024){
    bool csd = bid >= 512;
    int rb = (bid & 511) * 16;
    const float* A   = csd ? C : V;
    int K            = csd ? 64 : 256;
    const float2* st = (const float2*)(ws + (csd ? WS_STATSC : WS_STATSV));
    const float* g   = csd ? cgam : vg;
    const float* bb  = csd ? cbet : vb;
    const u16* Wt    = (const u16*)(ws + (csd ? WS_WT_CQK : WS_WT_VQK));
    const float* bias= csd ? bcqk : bvqk;
    const float* rms = csd ? rmsc : rmsv;
    int dOff         = csd ? 64 : 0;

    int row = rb + c;
    float2 stt = st[row];
    int j0 = w * 128;                 // wave = 128-col group of the 512

    f32x4 acc[8];
    #pragma unroll
    for (int f=0; f<8; f++){ f32x4 z = {0.f,0.f,0.f,0.f}; acc[f] = z; }

    int nkc = K >> 5;
    for (int kc=0; kc<nkc; kc++){
      int k0 = kc*32 + q*8;
      s16x8 af = ln_frag(A, g, bb, row*K, k0, stt);
      #pragma unroll
      for (int f=0; f<8; f++){
        s16x8 bfr = *(const s16x8*)(Wt + (j0 + f*16 + c)*K + k0);
        acc[f] = mfma16(af, bfr, acc[f]);
      }
    }

    float ss[4] = {0.f,0.f,0.f,0.f};
    float rsv[8];
    #pragma unroll
    for (int f=0; f<8; f++){
      int j = j0 + f*16 + c;
      float bsv = bias[j]; rsv[f] = rms[j];
      #pragma unroll
      for (int i=0;i<4;i++){ acc[f][i] += bsv; ss[i] += acc[f][i]*acc[f][i]; }
    }
    #pragma unroll
    for (int d=1; d<16; d<<=1){
      #pragma unroll
      for (int i=0;i<4;i++) ss[i] += __shfl_xor(ss[i], d);
    }
    if (c == 0){
      #pragma unroll
      for (int i=0;i<4;i++) ssl[w][q*4 + i] = ss[i];
    }
    __syncthreads();
    float rmsr[4];
    #pragma unroll
    for (int i=0;i<4;i++){
      int rl = q*4 + i;
      float tot = ssl[0][rl] + ssl[1][rl] + ssl[2][rl] + ssl[3][rl];
      rmsr[i] = rsqrtf(tot * (1.0f/512.0f) + 1e-6f);
    }
    u16* dstb = (u16*)(ws + (w < 2 ? WS_Q : WS_K));
    // fold 1/sqrt(64) AND log2(e) into Q so attention uses exp2 with no extra mult
    float qs = (w < 2) ? 0.125f*1.44269504f : 1.0f;
    #pragma unroll
    for (int f=0; f<8; f++){
      int jj = (j0 + f*16 + c) & 255;      // col within Q or K half
      int head = jj >> 6, dd = (jj & 63) + dOff;
      #pragma unroll
      for (int i=0;i<4;i++){
        int r = rb + q*4 + i;
        int b_ = r >> 11, n = r & 2047;
        dstb[((b_*4 + head)*2048 + n)*128 + dd] = f2bf(acc[f][i]*rmsr[i]*rsv[f]*qs);
      }
    }
  } else {
    int vb2 = bid - 1024;
    bool csd = vb2 >= 256;
    int rb = (vb2 & 255) * 32;
    const float* A   = csd ? C : V;
    int K            = csd ? 64 : 256;
    const float2* st = (const float2*)(ws + (csd ? WS_STATSC : WS_STATSV));
    const float* g   = csd ? cgam : vg;
    const float* bb  = csd ? cbet : vb;
    const u16* Wt    = (const u16*)(ws + (csd ? WS_WT_CV : WS_WT_VV));
    const float* bias= csd ? bcv : bvv;
    int dOff         = csd ? 64 : 0;

    int s = w & 1, cgp = w >> 1;       // 2 slabs x 2 colgroups(128)
    int r0 = rb + s*16, row = r0 + c;
    float2 stt = st[row];
    int j0 = cgp * 128;

    f32x4 acc[8];
    #pragma unroll
    for (int f=0; f<8; f++){ f32x4 z = {0.f,0.f,0.f,0.f}; acc[f] = z; }

    int nkc = K >> 5;
    for (int kc=0; kc<nkc; kc++){
      int k0 = kc*32 + q*8;
      s16x8 af = ln_frag(A, g, bb, row*K, k0, stt);
      #pragma unroll
      for (int f=0; f<8; f++){
        s16x8 bfr = *(const s16x8*)(Wt + (j0 + f*16 + c)*K + k0);
        acc[f] = mfma16(af, bfr, acc[f]);
      }
    }
    u16* vt = (u16*)(ws + WS_VT);
    int r = r0 + q*4;
    int b_ = r >> 11, n = r & 2047;
    // permute n within its 32-block so k_attn's in-register P (kv order
    // {q*4+i, 16+q*4+i} per A-frag slot group) matches V's stored order:
    // stored pos <- token m via pos = ((m&15)>>2)*8 + (m>>4)*4 + (m&3); m&3==0 here.
    int m = n & 31;
    int nper = (n & ~31) | (((m & 15) >> 2)*8 + (m >> 4)*4);
    #pragma unroll
    for (int f=0; f<8; f++){
      int j = j0 + f*16 + c;
      float bv_ = bias[j];
      int head = j >> 6, dd = (j & 63) + dOff;
      ushort4 pk;
      pk.x = f2bf(acc[f][0] + bv_); pk.y = f2bf(acc[f][1] + bv_);
      pk.z = f2bf(acc[f][2] + bv_); pk.w = f2bf(acc[f][3] + bv_);
      *(ushort4*)(vt + ((b_*4 + head)*128 + dd)*2048 + nper) = pk;
    }
  }
}

// ---------------- flash attention v5b: KV-split + in-register softmax.
// 512 blocks x 4 waves. Wave (g,h): g = Q-subblock (32 rows as 2x16), h = KV half (32 tiles).
// v5 design: swapped QK^T (mfma(K,Q)) makes lane (c,q) hold S[qrow=c][kv={f*16+q*4+i}]
// lane-locally; the PV A-fragment is packed in-register (no Ps LDS round-trip). The kv
// slot-order mismatch is folded into k_proj's V^T store (bijective n-permute per 32-block).
// v5b fix (round-3 fail post-mortem): v_cvt_pk_bf16_f32 inline asm was the only
// numerically-unverifiable component (operand order / rounding); replaced with known-RNE
// f2bf pair packing — bit-identical numerics to the passing round-2 kernel.
__global__ __launch_bounds__(256, 2) void k_attn(char* ws){
  const u16* Qw = (const u16*)(ws + WS_Q);
  const u16* Kw = (const u16*)(ws + WS_K);
  const u16* Vt = (const u16*)(ws + WS_VT);
  u16* Ov = (u16*)(ws + WS_OV);
  u16* Oc = (u16*)(ws + WS_OC);
  // smem map (bytes): K stages [4][8192] at 0; V stages [4][8192] at 32768.
  // Total 65536. Merge phase overlays bytes [0, 34304).
  __shared__ char smem[65536];
  u16* sm16 = (u16*)smem;

  int bh = blockIdx.x & 15, qb = blockIdx.x >> 4;
  int tid = threadIdx.x, lane = tid & 63, w = tid >> 6;
  int c = lane & 15, q = lane >> 4;
  int g = w & 1, h = w >> 1, ht = tid & 127;
  int qr0 = qb*64 + g*32;

  // Q fragments (rows qr0 + s*16 + c), read-once from global; B-operand of swapped QK^T
  s16x8 qf[2][4];
  #pragma unroll
  for (int s=0;s<2;s++)
    #pragma unroll
    for (int kc=0;kc<4;kc++)
      qf[s][kc] = *(const s16x8*)(Qw + (bh*2048 + qr0 + s*16 + c)*128 + kc*32 + q*8);

  // staging sources for this thread's half: chunk s = i*128 + ht, XOR pre-swizzle.
  const u16* ksrc[4]; const u16* vsrc[4];
  #pragma unroll
  for (int i=0;i<4;i++){
    int sc = i*128 + ht;
    { int r = sc >> 4, j = (sc & 15) ^ (r & 15);        // K: 32 rows x 16 chunks
      ksrc[i] = Kw + (bh*2048 + r)*128 + j*8; }
    { int r = sc >> 2, j = (sc & 3) ^ ((r >> 1) & 3);   // V: 128 rows x 4 chunks
      vsrc[i] = Vt + (bh*128 + r)*2048 + j*8; }
  }

  f32x4 o[2][8];
  float lsum[2] = {0.f, 0.f};        // per-lane partial row-sum for qrow=c (per subgroup)
  #pragma unroll
  for (int s=0;s<2;s++)
    #pragma unroll
    for (int f8=0;f8<8;f8++){ f32x4 z = {0.f,0.f,0.f,0.f}; o[s][f8] = z; }

  // stage tile t (absolute) into this half's buffer buf via async DMA (linear LDS dest).
  auto stage = [&](int buf, int t){
    u16* kd = sm16 + (h*2+buf)*4096;
    u16* vd = sm16 + 16384 + (h*2+buf)*4096;
    #pragma unroll
    for (int i=0;i<4;i++){
      async16(ksrc[i] + t*4096, kd + (i*128+ht)*8);   // K tile stride: 32 rows * 128
      async16(vsrc[i] + t*32,   vd + (i*128+ht)*8);   // V tile stride: 32 cols
    }
  };

  auto step = [&](int bi, int tt){
    int t = h*32 + tt;
    __syncthreads();                 // this half's buf bi staged (vmcnt(0) drained here)
    if (tt < 31) stage(bi^1, t+1);   // issue next-tile DMA; lands before next barrier

    const u16* kb = sm16 + (h*2+bi)*4096;
    const u16* vb = sm16 + 16384 + (h*2+bi)*4096;
    // K fragments: row f*16+c, chunk kc*4+q, swizzle ^c — shared by both Q-subgroups
    s16x8 kf[2][4];
    #pragma unroll
    for (int f=0;f<2;f++)
      #pragma unroll
      for (int kc=0;kc<4;kc++)
        kf[f][kc] = *(const s16x8*)(kb + ((f*16+c)*16 + (((kc*4+q) ^ c) & 15))*8);
    // V fragments: row f8*16+c, chunk q, swizzle ^((c>>1)&3)
    s16x8 vf[8];
    #pragma unroll
    for (int f8=0;f8<8;f8++)
      vf[f8] = *(const s16x8*)(vb + ((f8*16+c)*4 + ((q ^ ((c>>1)&3)) & 3))*8);

    // swapped QK^T: A=K, B=Q  ->  lane (c,q) holds S[qrow=c][kv=f*16+q*4+i]
    f32x4 sfr[2][2];
    #pragma unroll
    for (int s=0;s<2;s++)
      #pragma unroll
      for (int f=0;f<2;f++){ f32x4 z = {0.f,0.f,0.f,0.f}; sfr[s][f] = z; }
    #pragma unroll
    for (int s=0;s<2;s++)
      #pragma unroll
      for (int f=0;f<2;f++)
        #pragma unroll
        for (int kc=0;kc<4;kc++)
          sfr[s][f] = mfma16(kf[f][kc], qf[s][kc], sfr[s][f]);

    // in-register softmax numerator + PV (no LDS round-trip; RNE f2bf pair packing)
    #pragma unroll
    for (int s=0;s<2;s++){
      float p0 = exp2f(sfr[s][0][0]), p1 = exp2f(sfr[s][0][1]);
      float p2 = exp2f(sfr[s][0][2]), p3 = exp2f(sfr[s][0][3]);
      float p4 = exp2f(sfr[s][1][0]), p5 = exp2f(sfr[s][1][1]);
      float p6 = exp2f(sfr[s][1][2]), p7 = exp2f(sfr[s][1][3]);
      lsum[s] += ((p0+p1)+(p2+p3)) + ((p4+p5)+(p6+p7));
      union { u32 u[4]; s16x8 v; } pa;
      pa.u[0] = (u32)f2bf(p0) | ((u32)f2bf(p1) << 16);
      pa.u[1] = (u32)f2bf(p2) | ((u32)f2bf(p3) << 16);
      pa.u[2] = (u32)f2bf(p4) | ((u32)f2bf(p5) << 16);
      pa.u[3] = (u32)f2bf(p6) | ((u32)f2bf(p7) << 16);
      // pa element order matches V^T's permuted n-order (see k_proj)
      #pragma unroll
      for (int f8=0;f8<8;f8++)
        o[s][f8] = mfma16(pa.v, vf[f8], o[s][f8]);
    }
  };

  stage(0, h*32);                    // prologue: this half's first tile -> buf 0
  for (int tt=0; tt<32; tt+=2){
    step(0, tt);
    step(1, tt+1);
  }

  // ---- merge the two KV halves (f32, via LDS) ----
  __syncthreads();                   // all tile compute done; staging buffers free
  float* mg = (float*)smem;          // [2 g][64 lane] x 67 floats (64 o + 2 lsum, stride 67)
  if (h == 1){
    float* d = mg + (g*64 + lane)*67;
    #pragma unroll
    for (int s=0;s<2;s++)
      #pragma unroll
      for (int f8=0;f8<8;f8++)
        #pragma unroll
        for (int i=0;i<4;i++) d[(s*8+f8)*4 + i] = o[s][f8][i];
    d[64] = lsum[0]; d[65] = lsum[1];
  }
  __syncthreads();
  if (h == 0){
    float* d = mg + (g*64 + lane)*67;
    #pragma unroll
    for (int s=0;s<2;s++)
      #pragma unroll
      for (int f8=0;f8<8;f8++)
        #pragma unroll
        for (int i=0;i<4;i++) o[s][f8][i] += d[(s*8+f8)*4 + i];
    lsum[0] += d[64]; lsum[1] += d[65];

    // full row sums: partials live across q-groups -> reduce over lanes ^16, ^32
    #pragma unroll
    for (int s=0;s<2;s++){
      lsum[s] += __shfl_xor(lsum[s], 16);
      lsum[s] += __shfl_xor(lsum[s], 32);
    }

    int b_ = bh >> 2, hh = bh & 3;
    #pragma unroll
    for (int s=0;s<2;s++){
      float inv[4];
      #pragma unroll
      for (int i=0;i<4;i++) inv[i] = 1.0f/__shfl(lsum[s], q*4 + i);  // row q*4+i total
      #pragma unroll
      for (int f8=0;f8<8;f8++){
        int col = f8*16 + c;
        u16* dst = (col < 64) ? Ov : Oc;
        int ddim = col & 63;
        #pragma unroll
        for (int i=0;i<4;i++){
          int n = qr0 + s*16 + q*4 + i;
          dst[(b_*2048 + n)*256 + hh*64 + ddim] = f2bf(o[s][f8][i]*inv[i]);
        }
      }
    }
  }
}

// ---------------- fused output projections v2 (more waves):
// bids [0,512) N=256 16-row blocks (4 waves x 64-col groups); [512,640) N=64 64-row blocks.
__global__ __launch_bounds__(256) void k_out(const u16* Av, const u16* Wtv, const float* bv,
                                             const u16* Ac, const u16* Wtc, const float* bc,
                                             float* out){
  int bid = blockIdx.x;
  int tid = threadIdx.x, lane = tid & 63, w = tid >> 6;
  int c = lane & 15, q = lane >> 4;
  if (bid < 512){
    int rb = bid * 16;
    int row = rb + c;
    int j0 = w * 64;
    f32x4 acc[4];
    #pragma unroll
    for (int f=0; f<4; f++){ f32x4 z = {0.f,0.f,0.f,0.f}; acc[f] = z; }
    for (int kc=0; kc<8; kc++){
      int k0 = kc*32 + q*8;
      s16x8 af = *(const s16x8*)(Av + row*256 + k0);
      #pragma unroll
      for (int f=0; f<4; f++){
        s16x8 bfr = *(const s16x8*)(Wtv + (j0 + f*16 + c)*256 + k0);
        acc[f] = mfma16(af, bfr, acc[f]);
      }
    }
    #pragma unroll
    for (int f=0; f<4; f++){
      int j = j0 + f*16 + c;
      float bb = bv[j];
      #pragma unroll
      for (int i=0;i<4;i++)
        out[(rb + q*4 + i)*256 + j] = acc[f][i] + bb;
    }
  } else {
    int rb = (bid - 512) * 64;
    int r0 = rb + w*16, row = r0 + c;
    f32x4 acc[4];
    #pragma unroll
    for (int f=0; f<4; f++){ f32x4 z = {0.f,0.f,0.f,0.f}; acc[f] = z; }
    for (int kc=0; kc<8; kc++){
      int k0 = kc*32 + q*8;
      s16x8 af = *(const s16x8*)(Ac + row*256 + k0);
      #pragma unroll
      for (int f=0; f<4; f++){
        s16x8 bfr = *(const s16x8*)(Wtc + (f*16 + c)*256 + k0);
        acc[f] = mfma16(af, bfr, acc[f]);
      }
    }
    float* oc = out + 2097152;
    #pragma unroll
    for (int f=0; f<4; f++){
      int j = f*16 + c;
      float bb = bc[j];
      #pragma unroll
      for (int i=0;i<4;i++)
        oc[(r0 + q*4 + i)*64 + j] = acc[f][i] + bb;
    }
  }
}

extern "C" void kernel_launch(void* const* d_in, const int* in_sizes, int n_in,
                              void* d_out, int out_size, void* d_ws, size_t ws_size,
                              hipStream_t stream){
  (void)in_sizes; (void)n_in; (void)out_size; (void)ws_size;
  const float* V    = (const float*)d_in[0];
  const float* C    = (const float*)d_in[1];
  const float* vng  = (const float*)d_in[2];
  const float* vnb  = (const float*)d_in[3];
  const float* cng  = (const float*)d_in[4];
  const float* cnb  = (const float*)d_in[5];
  const float* Wvqk = (const float*)d_in[6];
  const float* bvqk = (const float*)d_in[7];
  const float* rmsv = (const float*)d_in[8];
  const float* Wcqk = (const float*)d_in[9];
  const float* bcqk = (const float*)d_in[10];
  const float* rmsc = (const float*)d_in[11];
  const float* Wvv  = (const float*)d_in[12];
  const float* bvv  = (const float*)d_in[13];
  const float* Wcv  = (const float*)d_in[14];
  const float* bcv  = (const float*)d_in[15];
  const float* Wov  = (const float*)d_in[16];
  const float* bov  = (const float*)d_in[17];
  const float* Woc  = (const float*)d_in[18];
  const float* boc  = (const float*)d_in[19];
  char* ws = (char*)d_ws;
  float* out = (float*)d_out;

  k_prep<<<4256, 256, 0, stream>>>(V, C, Wvqk, Wcqk, Wvv, Wcv, Wov, Woc, ws);
  k_proj<<<1536, 256, 0, stream>>>(V, C, vng, vnb, cng, cnb,
                                   bvqk, bcqk, rmsv, rmsc, bvv, bcv, ws);
  k_attn<<<512, 256, 0, stream>>>(ws);
  k_out<<<640, 256, 0, stream>>>((const u16*)(ws + WS_OV), (const u16*)(ws + WS_WT_OV), bov,
                                 (const u16*)(ws + WS_OC), (const u16*)(ws + WS_WT_OC), boc,
                                 out);
}

// Round 6
// 203.296 us; speedup vs baseline: 1.1247x; 1.0582x over previous
//
#include <hip/hip_runtime.h>

typedef unsigned short u16;
typedef unsigned int   u32;
typedef short s16x8 __attribute__((ext_vector_type(8)));   // 8 x bf16 (4 VGPRs)
typedef float f32x4 __attribute__((ext_vector_type(4)));

// ---- workspace layout (bytes); total footprint 34,340,864 (proven safe) ----
#define WS_STATSV 0          // (unused after v6)
#define WS_STATSC 65536      // (unused after v6)
#define WS_WT_VQK 131072     // [512][256] bf16
#define WS_WT_CQK 393216     // [512][64]
#define WS_WT_VV  458752     // [256][256]
#define WS_WT_CV  589824     // [256][64]
#define WS_WT_OV  622592     // [256][256]
#define WS_WT_OC  753664     // [64][256]
#define WS_Q      786432     // [16][2048][128] bf16  (qv|qc per head; Q pre-scaled by log2e/8)
#define WS_K      9175040    // frag-major K: [16 bh][64 t][2 f][4 kc][64 lane][8] bf16 (512KB/bh)
#define WS_VT     17563648   // frag-major V: [16 bh][64 t][8 f8][64 lane][8] bf16 (sigma-permuted kv)
#define WS_OV     25952256   // [8192][256] bf16 attn-out V  (pre-attn: Vn, LN'd V bf16 [8192][256])
#define WS_OC     30146560   // [8192][256] bf16 attn-out C  (pre-attn: Cn, LN'd C bf16 [8192][64])

__device__ __forceinline__ float bf2f(u16 h){
  union { u32 u; float f; } x; x.u = ((u32)h) << 16; return x.f;
}
__device__ __forceinline__ u16 f2bf(float f){
  union { float f; u32 u; } x; x.f = f;
  u32 u = x.u; u += 0x7fffu + ((u >> 16) & 1u);
  return (u16)(u >> 16);
}
__device__ __forceinline__ f32x4 mfma16(s16x8 a, s16x8 b, f32x4 c){
  return __builtin_amdgcn_mfma_f32_16x16x32_bf16(a, b, c, 0, 0, 0);
}

// ---------------- fused: LN stats+normalize (bids 0..4095) + weight transpose (4096..4255) ----
// v6: normalizes rows in-register and writes bf16 Vn/Cn (overlaid on WS_OV/WS_OC, which are
// dead until k_attn). Same fmaf chain as the old ln_frag -> bit-identical bf16 values.
__global__ __launch_bounds__(256) void k_prep(const float* V, const float* C,
    const float* vng, const float* vnb, const float* cng, const float* cnb,
    const float* Wvqk, const float* Wcqk, const float* Wvv, const float* Wcv,
    const float* Wov, const float* Woc, char* ws){
  int bid = blockIdx.x;
  if (bid < 4096){
    int wid = threadIdx.x >> 6, lane = threadIdx.x & 63;
    if (bid < 2048){
      int row = bid*4 + wid;
      const float4* p = (const float4*)(V + row*256);
      float4 v = p[lane];
      float s = v.x+v.y+v.z+v.w, s2 = v.x*v.x+v.y*v.y+v.z*v.z+v.w*v.w;
      for (int d=1; d<64; d<<=1){ s += __shfl_xor(s,d); s2 += __shfl_xor(s2,d); }
      float m = s*(1.0f/256.0f); float var = s2*(1.0f/256.0f) - m*m; if (var < 0.f) var = 0.f;
      float rstd = rsqrtf(var + 1e-5f), nb = -m*rstd;
      float4 gg = ((const float4*)vng)[lane];
      float4 bb = ((const float4*)vnb)[lane];
      ushort4 pk;
      pk.x = f2bf(fmaf(fmaf(v.x, rstd, nb), gg.x, bb.x));
      pk.y = f2bf(fmaf(fmaf(v.y, rstd, nb), gg.y, bb.y));
      pk.z = f2bf(fmaf(fmaf(v.z, rstd, nb), gg.z, bb.z));
      pk.w = f2bf(fmaf(fmaf(v.w, rstd, nb), gg.w, bb.w));
      *(ushort4*)((u16*)(ws + WS_OV) + row*256 + lane*4) = pk;
    } else {
      int row = (bid-2048)*4 + wid;
      float x = C[row*64 + lane];
      float s = x, s2 = x*x;
      for (int d=1; d<64; d<<=1){ s += __shfl_xor(s,d); s2 += __shfl_xor(s2,d); }
      float m = s*(1.0f/64.0f); float var = s2*(1.0f/64.0f) - m*m; if (var < 0.f) var = 0.f;
      float rstd = rsqrtf(var + 1e-5f);
      float xn = fmaf(fmaf(x, rstd, -m*rstd), cng[lane], cnb[lane]);
      ((u16*)(ws + WS_OC))[row*64 + lane] = f2bf(xn);
    }
  } else {
    int tb = bid - 4096;
    const float* src; u16* dst; int K, N, rel;
    if      (tb <  64){ src=Wvqk; dst=(u16*)(ws+WS_WT_VQK); K=256; N=512; rel=tb;     }
    else if (tb <  80){ src=Wcqk; dst=(u16*)(ws+WS_WT_CQK); K=64;  N=512; rel=tb-64;  }
    else if (tb < 112){ src=Wvv;  dst=(u16*)(ws+WS_WT_VV);  K=256; N=256; rel=tb-80;  }
    else if (tb < 120){ src=Wcv;  dst=(u16*)(ws+WS_WT_CV);  K=64;  N=256; rel=tb-112; }
    else if (tb < 152){ src=Wov;  dst=(u16*)(ws+WS_WT_OV);  K=256; N=256; rel=tb-120; }
    else              { src=Woc;  dst=(u16*)(ws+WS_WT_OC);  K=256; N=64;  rel=tb-152; }
    int e = rel*2048 + threadIdx.x*8;
    int k = e / N, n0 = e % N;
    float4 t0 = *(const float4*)(src + e);
    float4 t1 = *(const float4*)(src + e + 4);
    dst[(n0+0)*K + k] = f2bf(t0.x);
    dst[(n0+1)*K + k] = f2bf(t0.y);
    dst[(n0+2)*K + k] = f2bf(t0.z);
    dst[(n0+3)*K + k] = f2bf(t0.w);
    dst[(n0+4)*K + k] = f2bf(t1.x);
    dst[(n0+5)*K + k] = f2bf(t1.y);
    dst[(n0+6)*K + k] = f2bf(t1.z);
    dst[(n0+7)*K + k] = f2bf(t1.w);
  }
}

// ---------------- fused projections v3: pure bf16 GEMM (LN precomputed in k_prep).
// bids [0,512) V-qk 16-row, [512,1024) C-qk 16-row, [1024,1280) V-v 32-row, [1280,1536) C-v 32-row.
// K and V^T are written in k_attn's fragment-major layouts (see WS_K / WS_VT).
__global__ __launch_bounds__(256) void k_proj(const float* bvqk, const float* bcqk,
    const float* rmsv, const float* rmsc, const float* bvv, const float* bcv, char* ws){
  __shared__ float ssl[4][16];
  int bid = blockIdx.x;
  int tid = threadIdx.x, lane = tid & 63, w = tid >> 6;
  int c = lane & 15, q = lane >> 4;

  if (bid < 1024){
    bool csd = bid >= 512;
    int rb = (bid & 511) * 16;
    const u16* An    = (const u16*)(ws + (csd ? WS_OC : WS_OV));   // Cn / Vn
    int K            = csd ? 64 : 256;
    const u16* Wt    = (const u16*)(ws + (csd ? WS_WT_CQK : WS_WT_VQK));
    const float* bias= csd ? bcqk : bvqk;
    const float* rms = csd ? rmsc : rmsv;
    int dOff         = csd ? 64 : 0;

    int row = rb + c;
    int j0 = w * 128;                 // wave = 128-col group of the 512

    f32x4 acc[8];
    #pragma unroll
    for (int f=0; f<8; f++){ f32x4 z = {0.f,0.f,0.f,0.f}; acc[f] = z; }

    int nkc = K >> 5;
    for (int kc=0; kc<nkc; kc++){
      int k0 = kc*32 + q*8;
      s16x8 af = *(const s16x8*)(An + row*K + k0);
      #pragma unroll
      for (int f=0; f<8; f++){
        s16x8 bfr = *(const s16x8*)(Wt + (j0 + f*16 + c)*K + k0);
        acc[f] = mfma16(af, bfr, acc[f]);
      }
    }

    float ss[4] = {0.f,0.f,0.f,0.f};
    float rsv[8];
    #pragma unroll
    for (int f=0; f<8; f++){
      int j = j0 + f*16 + c;
      float bsv = bias[j]; rsv[f] = rms[j];
      #pragma unroll
      for (int i=0;i<4;i++){ acc[f][i] += bsv; ss[i] += acc[f][i]*acc[f][i]; }
    }
    #pragma unroll
    for (int d=1; d<16; d<<=1){
      #pragma unroll
      for (int i=0;i<4;i++) ss[i] += __shfl_xor(ss[i], d);
    }
    if (c == 0){
      #pragma unroll
      for (int i=0;i<4;i++) ssl[w][q*4 + i] = ss[i];
    }
    __syncthreads();
    float rmsr[4];
    #pragma unroll
    for (int i=0;i<4;i++){
      int rl = q*4 + i;
      float tot = ssl[0][rl] + ssl[1][rl] + ssl[2][rl] + ssl[3][rl];
      rmsr[i] = rsqrtf(tot * (1.0f/512.0f) + 1e-6f);
    }
    if (w < 2){
      // Q: row-major [bh][n][128], pre-scaled by log2e/8
      u16* dstb = (u16*)(ws + WS_Q);
      const float qs = 0.125f*1.44269504f;
      #pragma unroll
      for (int f=0; f<8; f++){
        int jj = (j0 + f*16 + c) & 255;
        int head = jj >> 6, dd = (jj & 63) + dOff;
        #pragma unroll
        for (int i=0;i<4;i++){
          int r = rb + q*4 + i;
          int b_ = r >> 11, n = r & 2047;
          dstb[((b_*4 + head)*2048 + n)*128 + dd] = f2bf(acc[f][i]*rmsr[i]*rsv[f]*qs);
        }
      }
    } else {
      // K: fragment-major [bh][t][fK][kcK][lane(qK,cK)][eK]
      u16* kfb = (u16*)(ws + WS_K);
      #pragma unroll
      for (int f=0; f<8; f++){
        int jj = (j0 + f*16 + c) & 255;
        int head = jj >> 6, dd = (jj & 63) + dOff;
        int kcK = dd >> 5, qK = (dd >> 3) & 3, eK = dd & 7;
        #pragma unroll
        for (int i=0;i<4;i++){
          int r = rb + q*4 + i;
          int b_ = r >> 11, n = r & 2047;
          int t = n >> 5, fK = (n >> 4) & 1, cK = n & 15;
          kfb[(b_*4 + head)*262144 + t*4096 + (fK*4 + kcK)*512 + (qK*16 + cK)*8 + eK]
            = f2bf(acc[f][i]*rmsr[i]*rsv[f]);
        }
      }
    }
  } else {
    int vb2 = bid - 1024;
    bool csd = vb2 >= 256;
    int rb = (vb2 & 255) * 32;
    const u16* An    = (const u16*)(ws + (csd ? WS_OC : WS_OV));
    int K            = csd ? 64 : 256;
    const u16* Wt    = (const u16*)(ws + (csd ? WS_WT_CV : WS_WT_VV));
    const float* bias= csd ? bcv : bvv;
    int dOff         = csd ? 64 : 0;

    int s = w & 1, cgp = w >> 1;       // 2 slabs x 2 colgroups(128)
    int r0 = rb + s*16, row = r0 + c;
    int j0 = cgp * 128;

    f32x4 acc[8];
    #pragma unroll
    for (int f=0; f<8; f++){ f32x4 z = {0.f,0.f,0.f,0.f}; acc[f] = z; }

    int nkc = K >> 5;
    for (int kc=0; kc<nkc; kc++){
      int k0 = kc*32 + q*8;
      s16x8 af = *(const s16x8*)(An + row*K + k0);
      #pragma unroll
      for (int f=0; f<8; f++){
        s16x8 bfr = *(const s16x8*)(Wt + (j0 + f*16 + c)*K + k0);
        acc[f] = mfma16(af, bfr, acc[f]);
      }
    }
    // V: fragment-major [bh][t][f8][lane(qV,cV)][e], kv sigma-permuted:
    // stored (q,e): e<4 -> token q*4+e ; e>=4 -> token 16+q*4+(e-4)
    u16* vfb = (u16*)(ws + WS_VT);
    int r = r0 + q*4;
    int b_ = r >> 11, n = r & 2047;
    int t = n >> 5, m = n & 31;               // m&3 == 0
    int qV = (m < 16) ? (m >> 2) : ((m >> 2) - 4);
    int e0 = (m < 16) ? 0 : 4;
    #pragma unroll
    for (int f=0; f<8; f++){
      int j = j0 + f*16 + c;
      float bv_ = bias[j];
      int head = j >> 6, dd = (j & 63) + dOff;
      int f8 = dd >> 4, cV = dd & 15;
      ushort4 pk;
      pk.x = f2bf(acc[f][0] + bv_); pk.y = f2bf(acc[f][1] + bv_);
      pk.z = f2bf(acc[f][2] + bv_); pk.w = f2bf(acc[f][3] + bv_);
      *(ushort4*)(vfb + (b_*4 + head)*262144 + t*4096 + f8*512 + (qV*16 + cV)*8 + e0) = pk;
    }
  }
}

// ---------------- flash attention v6: zero-LDS, fragment-direct from L2.
// 512 blocks x 4 waves. Wave (g,h): g = Q-subblock (32 rows as 2x16), h = KV half (32 tiles).
// K/V are stored fragment-major by k_proj, so each fragment load is one coalesced 1KB
// global_load_dwordx4 (L2/L1-resident, 1MB per bh). No staging, no DMA, no loop barriers —
// register double-buffering prefetches tile t+1 while computing t. LDS only for the h-merge.
__global__ __launch_bounds__(256, 2) void k_attn(char* ws){
  const u16* Qw = (const u16*)(ws + WS_Q);
  const u16* KF = (const u16*)(ws + WS_K);
  const u16* VF = (const u16*)(ws + WS_VT);
  u16* Ov = (u16*)(ws + WS_OV);
  u16* Oc = (u16*)(ws + WS_OC);
  __shared__ float mg[2][64][67];   // 34,304 B merge buffer (stride 67: conflict-free)

  int bh = blockIdx.x & 15, qb = blockIdx.x >> 4;
  int tid = threadIdx.x, lane = tid & 63, w = tid >> 6;
  int c = lane & 15, q = lane >> 4;
  int g = w & 1, h = w >> 1;
  int qr0 = qb*64 + g*32;

  // Q fragments (rows qr0 + s*16 + c), read-once from global; B-operand of swapped QK^T
  s16x8 qf[2][4];
  #pragma unroll
  for (int s=0;s<2;s++)
    #pragma unroll
    for (int kc=0;kc<4;kc++)
      qf[s][kc] = *(const s16x8*)(Qw + (bh*2048 + qr0 + s*16 + c)*128 + kc*32 + q*8);

  const u16* kb = KF + bh*262144 + h*131072 + lane*8;   // tile stride 4096 u16
  const u16* vb = VF + bh*262144 + h*131072 + lane*8;

  f32x4 o[2][8];
  float lsum[2] = {0.f, 0.f};
  #pragma unroll
  for (int s=0;s<2;s++)
    #pragma unroll
    for (int f8=0;f8<8;f8++){ f32x4 z = {0.f,0.f,0.f,0.f}; o[s][f8] = z; }

  s16x8 kA[2][4], vA[8], kB[2][4], vB[8];

  auto loadT = [&](s16x8 (&kf)[2][4], s16x8 (&vf)[8], int tt){
    const u16* kt = kb + tt*4096;
    const u16* vt = vb + tt*4096;
    #pragma unroll
    for (int f=0;f<2;f++)
      #pragma unroll
      for (int kc=0;kc<4;kc++)
        kf[f][kc] = *(const s16x8*)(kt + (f*4+kc)*512);
    #pragma unroll
    for (int f8=0;f8<8;f8++)
      vf[f8] = *(const s16x8*)(vt + f8*512);
  };

  auto comp = [&](const s16x8 (&kf)[2][4], const s16x8 (&vf)[8]){
    // swapped QK^T: A=K, B=Q  ->  lane (c,q) holds S[qrow=c][kv=f*16+q*4+i]
    f32x4 sfr[2][2];
    #pragma unroll
    for (int s=0;s<2;s++)
      #pragma unroll
      for (int f=0;f<2;f++){ f32x4 z = {0.f,0.f,0.f,0.f}; sfr[s][f] = z; }
    #pragma unroll
    for (int s=0;s<2;s++)
      #pragma unroll
      for (int f=0;f<2;f++)
        #pragma unroll
        for (int kc=0;kc<4;kc++)
          sfr[s][f] = mfma16(kf[f][kc], qf[s][kc], sfr[s][f]);

    #pragma unroll
    for (int s=0;s<2;s++){
      float p0 = exp2f(sfr[s][0][0]), p1 = exp2f(sfr[s][0][1]);
      float p2 = exp2f(sfr[s][0][2]), p3 = exp2f(sfr[s][0][3]);
      float p4 = exp2f(sfr[s][1][0]), p5 = exp2f(sfr[s][1][1]);
      float p6 = exp2f(sfr[s][1][2]), p7 = exp2f(sfr[s][1][3]);
      lsum[s] += ((p0+p1)+(p2+p3)) + ((p4+p5)+(p6+p7));
      union { u32 u[4]; s16x8 v; } pa;
      pa.u[0] = (u32)f2bf(p0) | ((u32)f2bf(p1) << 16);
      pa.u[1] = (u32)f2bf(p2) | ((u32)f2bf(p3) << 16);
      pa.u[2] = (u32)f2bf(p4) | ((u32)f2bf(p5) << 16);
      pa.u[3] = (u32)f2bf(p6) | ((u32)f2bf(p7) << 16);
      #pragma unroll
      for (int f8=0;f8<8;f8++)
        o[s][f8] = mfma16(pa.v, vf[f8], o[s][f8]);
    }
  };

  loadT(kA, vA, 0);
  for (int tt=0; tt<32; tt+=2){
    loadT(kB, vB, tt+1);
    comp(kA, vA);
    if (tt+2 < 32) loadT(kA, vA, tt+2);
    comp(kB, vB);
  }

  // ---- merge the two KV halves (f32, via LDS) ----
  __syncthreads();
  if (h == 1){
    float* d = &mg[g][lane][0];
    #pragma unroll
    for (int s=0;s<2;s++)
      #pragma unroll
      for (int f8=0;f8<8;f8++)
        #pragma unroll
        for (int i=0;i<4;i++) d[(s*8+f8)*4 + i] = o[s][f8][i];
    d[64] = lsum[0]; d[65] = lsum[1];
  }
  __syncthreads();
  if (h == 0){
    float* d = &mg[g][lane][0];
    #pragma unroll
    for (int s=0;s<2;s++)
      #pragma unroll
      for (int f8=0;f8<8;f8++)
        #pragma unroll
        for (int i=0;i<4;i++) o[s][f8][i] += d[(s*8+f8)*4 + i];
    lsum[0] += d[64]; lsum[1] += d[65];

    // full row sums: partials live across q-groups -> reduce over lanes ^16, ^32
    #pragma unroll
    for (int s=0;s<2;s++){
      lsum[s] += __shfl_xor(lsum[s], 16);
      lsum[s] += __shfl_xor(lsum[s], 32);
    }

    int b_ = bh >> 2, hh = bh & 3;
    #pragma unroll
    for (int s=0;s<2;s++){
      float inv[4];
      #pragma unroll
      for (int i=0;i<4;i++) inv[i] = 1.0f/__shfl(lsum[s], q*4 + i);  // row q*4+i total
      #pragma unroll
      for (int f8=0;f8<8;f8++){
        int col = f8*16 + c;
        u16* dst = (col < 64) ? Ov : Oc;
        int ddim = col & 63;
        #pragma unroll
        for (int i=0;i<4;i++){
          int n = qr0 + s*16 + q*4 + i;
          dst[(b_*2048 + n)*256 + hh*64 + ddim] = f2bf(o[s][f8][i]*inv[i]);
        }
      }
    }
  }
}

// ---------------- fused output projections v2 (more waves):
// bids [0,512) N=256 16-row blocks (4 waves x 64-col groups); [512,640) N=64 64-row blocks.
__global__ __launch_bounds__(256) void k_out(const u16* Av, const u16* Wtv, const float* bv,
                                             const u16* Ac, const u16* Wtc, const float* bc,
                                             float* out){
  int bid = blockIdx.x;
  int tid = threadIdx.x, lane = tid & 63, w = tid >> 6;
  int c = lane & 15, q = lane >> 4;
  if (bid < 512){
    int rb = bid * 16;
    int row = rb + c;
    int j0 = w * 64;
    f32x4 acc[4];
    #pragma unroll
    for (int f=0; f<4; f++){ f32x4 z = {0.f,0.f,0.f,0.f}; acc[f] = z; }
    for (int kc=0; kc<8; kc++){
      int k0 = kc*32 + q*8;
      s16x8 af = *(const s16x8*)(Av + row*256 + k0);
      #pragma unroll
      for (int f=0; f<4; f++){
        s16x8 bfr = *(const s16x8*)(Wtv + (j0 + f*16 + c)*256 + k0);
        acc[f] = mfma16(af, bfr, acc[f]);
      }
    }
    #pragma unroll
    for (int f=0; f<4; f++){
      int j = j0 + f*16 + c;
      float bb = bv[j];
      #pragma unroll
      for (int i=0;i<4;i++)
        out[(rb + q*4 + i)*256 + j] = acc[f][i] + bb;
    }
  } else {
    int rb = (bid - 512) * 64;
    int r0 = rb + w*16, row = r0 + c;
    f32x4 acc[4];
    #pragma unroll
    for (int f=0; f<4; f++){ f32x4 z = {0.f,0.f,0.f,0.f}; acc[f] = z; }
    for (int kc=0; kc<8; kc++){
      int k0 = kc*32 + q*8;
      s16x8 af = *(const s16x8*)(Ac + row*256 + k0);
      #pragma unroll
      for (int f=0; f<4; f++){
        s16x8 bfr = *(const s16x8*)(Wtc + (f*16 + c)*256 + k0);
        acc[f] = mfma16(af, bfr, acc[f]);
      }
    }
    float* oc = out + 2097152;
    #pragma unroll
    for (int f=0; f<4; f++){
      int j = f*16 + c;
      float bb = bc[j];
      #pragma unroll
      for (int i=0;i<4;i++)
        oc[(r0 + q*4 + i)*64 + j] = acc[f][i] + bb;
    }
  }
}

extern "C" void kernel_launch(void* const* d_in, const int* in_sizes, int n_in,
                              void* d_out, int out_size, void* d_ws, size_t ws_size,
                              hipStream_t stream){
  (void)in_sizes; (void)n_in; (void)out_size; (void)ws_size;
  const float* V    = (const float*)d_in[0];
  const float* C    = (const float*)d_in[1];
  const float* vng  = (const float*)d_in[2];
  const float* vnb  = (const float*)d_in[3];
  const float* cng  = (const float*)d_in[4];
  const float* cnb  = (const float*)d_in[5];
  const float* Wvqk = (const float*)d_in[6];
  const float* bvqk = (const float*)d_in[7];
  const float* rmsv = (const float*)d_in[8];
  const float* Wcqk = (const float*)d_in[9];
  const float* bcqk = (const float*)d_in[10];
  const float* rmsc = (const float*)d_in[11];
  const float* Wvv  = (const float*)d_in[12];
  const float* bvv  = (const float*)d_in[13];
  const float* Wcv  = (const float*)d_in[14];
  const float* bcv  = (const float*)d_in[15];
  const float* Wov  = (const float*)d_in[16];
  const float* bov  = (const float*)d_in[17];
  const float* Woc  = (const float*)d_in[18];
  const float* boc  = (const float*)d_in[19];
  char* ws = (char*)d_ws;
  float* out = (float*)d_out;

  k_prep<<<4256, 256, 0, stream>>>(V, C, vng, vnb, cng, cnb,
                                   Wvqk, Wcqk, Wvv, Wcv, Wov, Woc, ws);
  k_proj<<<1536, 256, 0, stream>>>(bvqk, bcqk, rmsv, rmsc, bvv, bcv, ws);
  k_attn<<<512, 256, 0, stream>>>(ws);
  k_out<<<640, 256, 0, stream>>>((const u16*)(ws + WS_OV), (const u16*)(ws + WS_WT_OV), bov,
                                 (const u16*)(ws + WS_OC), (const u16*)(ws + WS_WT_OC), boc,
                                 out);
}